// Round 11
// baseline (2048.180 us; speedup 1.0000x reference)
//
#include <hip/hip_runtime.h>
#include <hip/hip_bf16.h>

// FilterModule: 7x MHA fusion pipeline, bf16 MFMA + flash attention v10.
// v10 = v9 pipeline + 2-qfrag flash retry with the VGPR fix that R4-R6 lacked:
// 256-thr blocks + __launch_bounds__(256,1) -> measured 256-VGPR cap (R6).
// 4 waves x 32 q; KVB=64 dbuf (136KB LDS, 1 block/CU, grid 256*batch);
// LDS P-repack with validated pswz XOR; per-tile 64 ds_read : 128 MFMA
// (halved LDS traffic per unit work vs v7's 16q waves).

typedef __attribute__((ext_vector_type(8))) short short8;
typedef __attribute__((ext_vector_type(4))) float f32x4;
typedef unsigned long long ull;
typedef long long ll;

namespace {
constexpr int NTOK = 4096;
constexpr int EMB  = 1024;
constexpr int QTY  = 512;
}

__device__ __forceinline__ float bf2f(unsigned short u) {
    union { float f; unsigned int i; } x; x.i = ((unsigned int)u) << 16; return x.f;
}
__device__ __forceinline__ unsigned short f2bf(float f) {
    union { float f; unsigned int i; } x; x.f = f;
    unsigned int r = x.i + 0x7fffu + ((x.i >> 16) & 1u);
    return (unsigned short)(r >> 16);
}
__device__ __forceinline__ unsigned int cvt_pk_bf16(float a, float b) {
    unsigned int d;
    asm("v_cvt_pk_bf16_f32 %0, %1, %2" : "=v"(d) : "v"(a), "v"(b));
    return d;
}

#define GLOAD_LDS16(g, l) __builtin_amdgcn_global_load_lds( \
    (const __attribute__((address_space(1))) void*)(g),     \
    (__attribute__((address_space(3))) void*)(l), 16, 0, 0)

// ---------------------------------------------------------------------------
// MFMA GEMM (B^T layout): C[m][n] = alpha*sum_k A[m][k]*B[n][k] (+epilogue).
// 128x128 tile, BK=32, 256 thr. Signed z-strides for batched launches.
// SPLITS: 1 = Ah*Bh; 2 = Ah*(Bh+Bl); 3 = (Ah+Al)*(Bh+Bl) minus ll term.
// OUTM: 0=f32, 1=bf16, 2=split pair. biasRow: bias indexed by row (else col).
template<int SPLITS, int OUTM>
__global__ __launch_bounds__(256)
void gemm_mfma(const unsigned short* __restrict__ Ah, const unsigned short* __restrict__ Al,
               int lda, ll sAz,
               const unsigned short* __restrict__ Bh, const unsigned short* __restrict__ Bl,
               int ldb, ll sBz,
               void* __restrict__ Cp, void* __restrict__ Clp,
               int ldc, ll sCz,
               int K, float alpha, const float* __restrict__ bias, int biasRow,
               const unsigned short* __restrict__ resH, const unsigned short* __restrict__ resL,
               ll sRz, int resMode)
{
    constexpr int NTILES = (SPLITS == 3 ? 4 : (SPLITS == 2 ? 3 : 2));
    constexpr int TSZ = 128 * 32;
    __shared__ unsigned short lds[NTILES * TSZ];  // Ah | Bh | [Bl] | [Al]
    const int tid  = threadIdx.x;
    const int brow = blockIdx.y * 128;
    const int bcol = blockIdx.x * 128;
    const ll   z   = blockIdx.z;
    Ah += z * sAz; Bh += z * sBz;
    if constexpr (SPLITS == 3) Al += z * sAz;
    if constexpr (SPLITS >= 2) Bl += z * sBz;

    const int lane = tid & 63;
    const int wv = tid >> 6, wr = wv >> 1, wc = wv & 1;
    const int l15 = lane & 15, l4 = lane >> 4;

    f32x4 acc[4][4];
    #pragma unroll
    for (int m = 0; m < 4; ++m)
        #pragma unroll
        for (int n = 0; n < 4; ++n) acc[m][n] = (f32x4){0.f, 0.f, 0.f, 0.f};

    for (int k0 = 0; k0 < K; k0 += 32) {
        #pragma unroll
        for (int i = 0; i < 2; ++i) {
            int idx = tid + i * 256;
            int row = idx >> 2;
            int kc  = (idx & 3) ^ ((row >> 1) & 3);
            GLOAD_LDS16(Ah + (ull)(brow + row) * lda + k0 + kc * 8, &lds[idx * 8]);
            GLOAD_LDS16(Bh + (ull)(bcol + row) * ldb + k0 + kc * 8, &lds[TSZ + idx * 8]);
            if constexpr (SPLITS >= 2)
                GLOAD_LDS16(Bl + (ull)(bcol + row) * ldb + k0 + kc * 8, &lds[2 * TSZ + idx * 8]);
            if constexpr (SPLITS == 3)
                GLOAD_LDS16(Al + (ull)(brow + row) * lda + k0 + kc * 8, &lds[3 * TSZ + idx * 8]);
        }
        __syncthreads();

        short8 ah[4], bh[4], bl2[4], al2[4];
        #pragma unroll
        for (int m = 0; m < 4; ++m) {
            int rr = wr * 64 + m * 16 + l15;
            int sl = l4 ^ ((rr >> 1) & 3);
            int off = rr * 32 + sl * 8;
            ah[m] = *(const short8*)&lds[off];
            if constexpr (SPLITS == 3) al2[m] = *(const short8*)&lds[3 * TSZ + off];
        }
        #pragma unroll
        for (int n = 0; n < 4; ++n) {
            int rr = wc * 64 + n * 16 + l15;
            int sl = l4 ^ ((rr >> 1) & 3);
            int off = rr * 32 + sl * 8;
            bh[n] = *(const short8*)&lds[TSZ + off];
            if constexpr (SPLITS >= 2) bl2[n] = *(const short8*)&lds[2 * TSZ + off];
        }
        #pragma unroll
        for (int m = 0; m < 4; ++m)
            #pragma unroll
            for (int n = 0; n < 4; ++n) {
                acc[m][n] = __builtin_amdgcn_mfma_f32_16x16x32_bf16(ah[m], bh[n], acc[m][n], 0, 0, 0);
                if constexpr (SPLITS >= 2)
                    acc[m][n] = __builtin_amdgcn_mfma_f32_16x16x32_bf16(ah[m], bl2[n], acc[m][n], 0, 0, 0);
                if constexpr (SPLITS == 3)
                    acc[m][n] = __builtin_amdgcn_mfma_f32_16x16x32_bf16(al2[m], bh[n], acc[m][n], 0, 0, 0);
            }
        __syncthreads();
    }

    float* Cf = (float*)Cp + z * sCz;
    unsigned short* Ch = (unsigned short*)Cp + z * sCz;
    unsigned short* Cl = (unsigned short*)Clp + z * sCz;
    const unsigned short* rH = resH + z * sRz;
    const unsigned short* rL = resL + z * sRz;
    const int rowB = brow + wr * 64 + l4 * 4;
    const int colB = bcol + wc * 64 + l15;
    #pragma unroll
    for (int n = 0; n < 4; ++n) {
        int col = colB + n * 16;
        #pragma unroll
        for (int m = 0; m < 4; ++m) {
            #pragma unroll
            for (int r = 0; r < 4; ++r) {
                int row = rowB + m * 16 + r;
                ull ci = (ull)row * ldc + col;
                float v = acc[m][n][r] * alpha;
                if (bias) v += biasRow ? bias[row] : bias[col];
                if (resMode == 1)      v += bf2f(rH[ci]) + bf2f(rL[ci]);
                else if (resMode == 2) v *= bf2f(rH[ci]) + bf2f(rL[ci]);
                if constexpr (OUTM == 0)      Cf[ci] = v;
                else if constexpr (OUTM == 1) Ch[ci] = f2bf(v);
                else {
                    unsigned short h = f2bf(v);
                    Ch[ci] = h;
                    Cl[ci] = f2bf(v - bf2f(h));
                }
            }
        }
    }
}

// ---------------------------------------------------------------------------
// Flash attention v10. QK [batch][4096][2048] bf16; VT [batch][1024][4096].
// 4 waves x 32 q (2 q-frags/wave); 2-way KV split; KVB=64 dbuf.
// blockIdx.z = batch*4 + head. 256 thr, launch_bounds (256,1) -> 256 VGPR cap.
__global__ __launch_bounds__(256, 1)
void flash_attn(const unsigned short* __restrict__ QK,
                const unsigned short* __restrict__ VT,
                unsigned short* __restrict__ Opart, float* __restrict__ ml)
{
    constexpr int KVB = 64;
    constexpr int NTILE = 2048 / KVB;             // 32 tiles per block
    __shared__ unsigned short Kt[2][KVB * 256];   // 64 KB [kv][d], chunk-swizzled
    __shared__ unsigned short Vt[2][256 * KVB];   // 64 KB [d][kv], swizzled
    __shared__ unsigned short Pb[4 * 1024];       // 8 KB per-wave P repack

    const int tid = threadIdx.x;
    const int w = tid >> 6, lane = tid & 63;
    const int l15 = lane & 15, l4 = lane >> 4;
    const int qt = blockIdx.x, sp = blockIdx.y;
    const int zb = blockIdx.z, b = zb >> 2, h = zb & 3;
    const int qbase = qt * 128 + w * 32;
    const int kv0 = sp * 2048;
    const unsigned short* QKb = QK + (ull)b * NTOK * 2048;
    const unsigned short* VTb = VT + (ull)b * 1024 * 4096;
    unsigned short* Pw = &Pb[w * 1024];
    const int pswz = (l15 & 3) * 8;               // XOR swizzle, 8-short granular

    // Q B-fragments (2 q-frags x 8 k-chunks), pre-scaled by 1/16 (exact)
    short8 qreg[2][8];
    #pragma unroll
    for (int qf = 0; qf < 2; ++qf) {
        const unsigned short* qp = QKb + (ull)(qbase + qf * 16 + l15) * 2048 + h * 256;
        #pragma unroll
        for (int c = 0; c < 8; ++c) {
            short8 x = *(const short8*)&qp[c * 32 + l4 * 8];
            #pragma unroll
            for (int j = 0; j < 8; ++j)
                x[j] = (short)f2bf(bf2f((unsigned short)x[j]) * 0.0625f);
            qreg[qf][c] = x;
        }
    }

    f32x4 oacc[2][16];
    #pragma unroll
    for (int qf = 0; qf < 2; ++qf)
        #pragma unroll
        for (int dn = 0; dn < 16; ++dn) oacc[qf][dn] = (f32x4){0.f, 0.f, 0.f, 0.f};
    float m_r[2] = { -1e30f, -1e30f }, l_r[2] = { 0.f, 0.f };

    auto stage = [&](int t, int buf) {
        int base = kv0 + t * KVB;
        #pragma unroll
        for (int i = 0; i < 8; ++i) {       // K tile: 64 rows x 32 chunks
            int s = tid + i * 256;
            int r = s >> 5, c = s & 31;
            int c0 = c ^ (r & 7);
            GLOAD_LDS16(QKb + (ull)(base + r) * 2048 + 1024 + h * 256 + c0 * 8,
                        &Kt[buf][s * 8]);
        }
        #pragma unroll
        for (int i = 0; i < 8; ++i) {       // V^T tile: 256 rows x 8 chunks
            int s = tid + i * 256;
            int r = s >> 3, c = s & 7;
            int c0 = c ^ (r & 7);
            GLOAD_LDS16(VTb + (ull)(h * 256 + r) * 4096 + base + c0 * 8,
                        &Vt[buf][s * 8]);
        }
    };

    stage(0, 0);
    for (int t = 0; t < NTILE; ++t) {
        if (t + 1 < NTILE) {
            stage(t + 1, (t + 1) & 1);
            asm volatile("s_waitcnt vmcnt(16)");
        } else {
            asm volatile("s_waitcnt vmcnt(0)");
        }
        __builtin_amdgcn_s_barrier();

        const unsigned short* Kb = Kt[t & 1];
        const unsigned short* Vb = Vt[t & 1];

        // QK^T (swapped): sacc[qf][fk], lane: q=l15, kv=fk*16+l4*4+r
        f32x4 sacc[2][4];
        #pragma unroll
        for (int qf = 0; qf < 2; ++qf)
            #pragma unroll
            for (int fk = 0; fk < 4; ++fk) sacc[qf][fk] = (f32x4){0.f, 0.f, 0.f, 0.f};

        __builtin_amdgcn_s_setprio(1);
        #pragma unroll
        for (int fk = 0; fk < 4; ++fk) {
            int r = fk * 16 + l15;
            int rx = r & 7;
            #pragma unroll
            for (int c = 0; c < 8; ++c) {
                int ch = (4 * c + l4) ^ rx;
                short8 kf = *(const short8*)&Kb[r * 256 + ch * 8];
                sacc[0][fk] = __builtin_amdgcn_mfma_f32_16x16x32_bf16(kf, qreg[0][c], sacc[0][fk], 0, 0, 0);
                sacc[1][fk] = __builtin_amdgcn_mfma_f32_16x16x32_bf16(kf, qreg[1][c], sacc[1][fk], 0, 0, 0);
            }
        }
        __builtin_amdgcn_s_setprio(0);

        // online softmax per q-frag; exp overwrites sacc in place
        #pragma unroll
        for (int qf = 0; qf < 2; ++qf) {
            float tm = sacc[qf][0][0];
            #pragma unroll
            for (int fk = 0; fk < 4; ++fk)
                #pragma unroll
                for (int rr = 0; rr < 4; ++rr) tm = fmaxf(tm, sacc[qf][fk][rr]);
            tm = fmaxf(tm, __shfl_xor(tm, 16));
            tm = fmaxf(tm, __shfl_xor(tm, 32));

            // defer-max: rescale only when tile max exceeds running max + THR
            if (!__all(tm <= m_r[qf] + 5.545f)) {
                float mnew = fmaxf(m_r[qf], tm);
                float corr = __expf(m_r[qf] - mnew);
                float c4[4];
                #pragma unroll
                for (int r = 0; r < 4; ++r) c4[r] = __shfl(corr, l4 * 4 + r);
                #pragma unroll
                for (int dn = 0; dn < 16; ++dn)
                    #pragma unroll
                    for (int r = 0; r < 4; ++r) oacc[qf][dn][r] *= c4[r];
                l_r[qf] *= corr;
                m_r[qf] = mnew;
            }

            float ls = 0.f;
            #pragma unroll
            for (int fk = 0; fk < 4; ++fk)
                #pragma unroll
                for (int rr = 0; rr < 4; ++rr) {
                    float e = __expf(sacc[qf][fk][rr] - m_r[qf]);
                    sacc[qf][fk][rr] = e; ls += e;
                }
            ls += __shfl_xor(ls, 16);
            ls += __shfl_xor(ls, 32);
            l_r[qf] += ls;
        }

        // PV per 32-kv chunk: swizzled LDS repack -> A-frags, then MFMA
        #pragma unroll
        for (int kvc = 0; kvc < 2; ++kvc) {
            #pragma unroll
            for (int qf = 0; qf < 2; ++qf)
                #pragma unroll
                for (int fh = 0; fh < 2; ++fh) {
                    int fk = kvc * 2 + fh;
                    uint2 wv;
                    wv.x = cvt_pk_bf16(sacc[qf][fk][0], sacc[qf][fk][1]);
                    wv.y = cvt_pk_bf16(sacc[qf][fk][2], sacc[qf][fk][3]);
                    *(uint2*)&Pw[(qf * 16 + l15) * 32 + ((fh * 16 + l4 * 4) ^ pswz)] = wv;
                }
            short8 pa0 = *(const short8*)&Pw[l15 * 32 + ((l4 * 8) ^ pswz)];
            short8 pa1 = *(const short8*)&Pw[(16 + l15) * 32 + ((l4 * 8) ^ pswz)];

            __builtin_amdgcn_s_setprio(1);
            #pragma unroll
            for (int dn = 0; dn < 16; ++dn) {
                int row = dn * 16 + l15;
                int ch = (kvc * 4 + l4) ^ (row & 7);
                short8 vf = *(const short8*)&Vb[row * 64 + ch * 8];
                oacc[0][dn] = __builtin_amdgcn_mfma_f32_16x16x32_bf16(pa0, vf, oacc[0][dn], 0, 0, 0);
                oacc[1][dn] = __builtin_amdgcn_mfma_f32_16x16x32_bf16(pa1, vf, oacc[1][dn], 0, 0, 0);
            }
            __builtin_amdgcn_s_setprio(0);
        }
        __builtin_amdgcn_s_barrier();
    }

    // epilogue: normalized O (bf16) + (m,l). lane: d=dn*16+l15, q=base+l4*4+r
    unsigned short* Ob = Opart + (((ull)b * 2 + sp) * 4 + h) * NTOK * 256;
    #pragma unroll
    for (int qf = 0; qf < 2; ++qf) {
        float inv = 1.f / l_r[qf];
        float i4[4];
        #pragma unroll
        for (int r = 0; r < 4; ++r) i4[r] = __shfl(inv, l4 * 4 + r);
        #pragma unroll
        for (int dn = 0; dn < 16; ++dn) {
            int d = dn * 16 + l15;
            #pragma unroll
            for (int r = 0; r < 4; ++r) {
                int q = qbase + qf * 16 + l4 * 4 + r;
                Ob[(ull)q * 256 + d] = f2bf(oacc[qf][dn][r] * i4[r]);
            }
        }
        if (l4 == 0) {
            float2* mlp = (float2*)ml + (((ull)b * 2 + sp) * 4 + h) * NTOK
                          + qbase + qf * 16 + l15;
            *mlp = make_float2(m_r[qf], l_r[qf]);
        }
    }
}

// ---------------------------------------------------------------------------
// merge 2 KV-split partials (normalized bf16) -> att bf16 (hi only).
// blockIdx.x = batch*4096 + q.
__global__ __launch_bounds__(256)
void flash_combine(const unsigned short* __restrict__ Opart, const float* __restrict__ ml,
                   unsigned short* __restrict__ attH)
{
    const int bx = blockIdx.x;
    const int b = bx >> 12, q = bx & 4095;
    const int t = threadIdx.x;
    const int h = t >> 6, d4 = (t & 63) * 4;

    float2 m0 = ((const float2*)ml)[(((ull)b * 2 + 0) * 4 + h) * NTOK + q];
    float2 m1 = ((const float2*)ml)[(((ull)b * 2 + 1) * 4 + h) * NTOK + q];
    float ms = fmaxf(m0.x, m1.x);
    float w0 = __expf(m0.x - ms) * m0.y;
    float w1 = __expf(m1.x - ms) * m1.y;
    float inv = 1.f / (w0 + w1);
    w0 *= inv; w1 *= inv;

    ushort4 o0 = *(const ushort4*)&Opart[((((ull)b * 2 + 0) * 4 + h) * NTOK + q) * 256 + d4];
    ushort4 o1 = *(const ushort4*)&Opart[((((ull)b * 2 + 1) * 4 + h) * NTOK + q) * 256 + d4];
    ushort4 ho;
    ho.x = f2bf(w0 * bf2f(o0.x) + w1 * bf2f(o1.x));
    ho.y = f2bf(w0 * bf2f(o0.y) + w1 * bf2f(o1.y));
    ho.z = f2bf(w0 * bf2f(o0.z) + w1 * bf2f(o1.z));
    ho.w = f2bf(w0 * bf2f(o0.w) + w1 * bf2f(o1.w));
    *(ushort4*)&attH[(ull)b * NTOK * EMB + (ull)q * EMB + h * 256 + d4] = ho;
}

// ---------------------------------------------------------------------------
template<bool F32IN>
__global__ __launch_bounds__(256)
void l2norm_rows(const float* __restrict__ inF, const unsigned short* __restrict__ inH,
                 const unsigned short* __restrict__ inL,
                 unsigned short* __restrict__ oH, unsigned short* __restrict__ oL)
{
    const ull row = blockIdx.x;
    const int t = threadIdx.x;
    const int lane = t & 63, wid = t >> 6;
    __shared__ float red[4];

    float v[4];
    if constexpr (F32IN) {
        float4 x = *(const float4*)&inF[row * EMB + t * 4];
        v[0] = x.x; v[1] = x.y; v[2] = x.z; v[3] = x.w;
    } else {
        ushort4 hh = *(const ushort4*)&inH[row * EMB + t * 4];
        ushort4 ll2 = *(const ushort4*)&inL[row * EMB + t * 4];
        v[0] = bf2f(hh.x) + bf2f(ll2.x); v[1] = bf2f(hh.y) + bf2f(ll2.y);
        v[2] = bf2f(hh.z) + bf2f(ll2.z); v[3] = bf2f(hh.w) + bf2f(ll2.w);
    }
    float ss = v[0] * v[0] + v[1] * v[1] + v[2] * v[2] + v[3] * v[3];
    #pragma unroll
    for (int o = 32; o > 0; o >>= 1) ss += __shfl_down(ss, o);
    if (lane == 0) red[wid] = ss;
    __syncthreads();
    ss = red[0] + red[1] + red[2] + red[3];

    float inv = 1.f / fmaxf(sqrtf(ss), 1e-8f);
    ushort4 ho, lo;
    float s0 = v[0] * inv, s1 = v[1] * inv, s2 = v[2] * inv, s3 = v[3] * inv;
    ho.x = f2bf(s0); lo.x = f2bf(s0 - bf2f(ho.x));
    ho.y = f2bf(s1); lo.y = f2bf(s1 - bf2f(ho.y));
    ho.z = f2bf(s2); lo.z = f2bf(s2 - bf2f(ho.z));
    ho.w = f2bf(s3); lo.w = f2bf(s3 - bf2f(ho.w));
    *(ushort4*)&oH[row * EMB + t * 4] = ho;
    *(ushort4*)&oL[row * EMB + t * 4] = lo;
}

__global__ __launch_bounds__(256)
void add_pos_pair(const float* __restrict__ in, const float* __restrict__ pos,
                  unsigned short* __restrict__ oH, unsigned short* __restrict__ oL)
{
    ull i = ((ull)blockIdx.x * 256 + threadIdx.x) * 4;
    float4 a = *(const float4*)&in[i];
    float4 p = *(const float4*)&pos[(int)(i & (EMB - 1))];
    float w[4] = { a.x + p.x, a.y + p.y, a.z + p.z, a.w + p.w };
    ushort4 ho, lo;
    ho.x = f2bf(w[0]); lo.x = f2bf(w[0] - bf2f(ho.x));
    ho.y = f2bf(w[1]); lo.y = f2bf(w[1] - bf2f(ho.y));
    ho.z = f2bf(w[2]); lo.z = f2bf(w[2] - bf2f(ho.z));
    ho.w = f2bf(w[3]); lo.w = f2bf(w[3] - bf2f(ho.w));
    *(ushort4*)&oH[i] = ho;
    *(ushort4*)&oL[i] = lo;
}

__global__ __launch_bounds__(256)
void split_pair(const float* __restrict__ in, unsigned short* __restrict__ oH,
                unsigned short* __restrict__ oL)
{
    ull i = ((ull)blockIdx.x * 256 + threadIdx.x) * 4;
    float4 a = *(const float4*)&in[i];
    float w[4] = { a.x, a.y, a.z, a.w };
    ushort4 ho, lo;
    ho.x = f2bf(w[0]); lo.x = f2bf(w[0] - bf2f(ho.x));
    ho.y = f2bf(w[1]); lo.y = f2bf(w[1] - bf2f(ho.y));
    ho.z = f2bf(w[2]); lo.z = f2bf(w[2] - bf2f(ho.z));
    ho.w = f2bf(w[3]); lo.w = f2bf(w[3] - bf2f(ho.w));
    *(ushort4*)&oH[i] = ho;
    *(ushort4*)&oL[i] = lo;
}

// f32 -> bf16 cast (hi only), 4 elems/thread
__global__ __launch_bounds__(256)
void cast_bf16(const float* __restrict__ in, unsigned short* __restrict__ out)
{
    ull i = ((ull)blockIdx.x * 256 + threadIdx.x) * 4;
    float4 a = *(const float4*)&in[i];
    ushort4 ho;
    ho.x = f2bf(a.x); ho.y = f2bf(a.y); ho.z = f2bf(a.z); ho.w = f2bf(a.w);
    *(ushort4*)&out[i] = ho;
}

// ---------------------------------------------------------------------------
namespace {

template<int S, int O>
inline void G(dim3 grid,
              const unsigned short* Ah, const unsigned short* Al, int lda, ll sAz,
              const unsigned short* Bh, const unsigned short* Bl, int ldb, ll sBz,
              void* Ch, void* Cl, int ldc, ll sCz,
              int K, float alpha, const float* bias, int biasRow,
              const unsigned short* rh, const unsigned short* rl, ll sRz, int rm,
              hipStream_t st)
{
    gemm_mfma<S, O><<<grid, dim3(256), 0, st>>>(Ah, Al, lda, sAz, Bh, Bl, ldb, sBz,
                                                Ch, Cl, ldc, sCz, K, alpha, bias, biasRow,
                                                rh, rl, sRz, rm);
}

struct Bufs {
    unsigned short *Ph[6], *Pl[6];
    unsigned short *ATTh, *QK, *VT, *Wih, *Woh, *Wol, *Opart;
    float *ml;
};

// batch mhas sharing (in_w,out_w): z in [0,batch). q input = qh + z*sQ,
// k/v input = kh + z*sK, dest = dsth/dstl + z*2TE, res = resh/resl + z*sR.
void run_mha(int batch,
             const unsigned short* qh, ll sQ,
             const unsigned short* kh, ll sK,
             const float* in_w, const float* in_b,
             const float* out_w, const float* out_b,
             unsigned short* dsth, unsigned short* dstl,
             const unsigned short* resh, const unsigned short* resl, ll sR, int resMode,
             const Bufs& B, bool convW, hipStream_t s)
{
    const ull EE = (ull)EMB * EMB;
    const ll  TE = (ll)NTOK * EMB;
    const ll  QKBS = (ll)NTOK * 2048;
    const ll  VTBS = (ll)1024 * 4096;
    if (convW) {
        cast_bf16<<<3 * EE / 1024, 256, 0, s>>>(in_w, B.Wih);
        split_pair<<<EE / 1024, 256, 0, s>>>(out_w, B.Woh, B.Wol);
    }
    // Q proj -> QK[b][:,0:1024]
    G<1, 1>(dim3(8, 32, batch), qh, nullptr, EMB, sQ, B.Wih, nullptr, EMB, 0,
            B.QK, nullptr, 2048, QKBS, EMB, 1.f, in_b, 0, nullptr, nullptr, 0, 0, s);
    // K proj -> QK[b][:,1024:2048]
    G<1, 1>(dim3(8, 32, batch), kh, nullptr, EMB, sK, B.Wih + EE, nullptr, EMB, 0,
            B.QK + 1024, nullptr, 2048, QKBS, EMB, 1.f, in_b + EMB, 0, nullptr, nullptr, 0, 0, s);
    // V^T proj: C[b][d][token] = Wv[d,:]·feat[token,:] + b_v[d]  (bias-row)
    G<1, 1>(dim3(32, 8, batch), B.Wih + 2 * EE, nullptr, EMB, 0, kh, nullptr, EMB, sK,
            B.VT, nullptr, 4096, VTBS, EMB, 1.f, in_b + 2 * EMB, 1, nullptr, nullptr, 0, 0, s);

    flash_attn<<<dim3(32, 2, 4 * batch), 256, 0, s>>>(B.QK, B.VT, B.Opart, B.ml);
    flash_combine<<<batch * NTOK, 256, 0, s>>>(B.Opart, B.ml, B.ATTh);

    // out-proj: A = att (hi only) x weight pair -> dest pair (+res epilogue)
    G<2, 2>(dim3(8, 32, batch), B.ATTh, nullptr, EMB, TE, B.Woh, B.Wol, EMB, 0,
            dsth, dstl, EMB, 2 * TE, EMB, 1.f, out_b, 0, resh, resl, sR, resMode, s);
}

} // namespace

extern "C" void kernel_launch(void* const* d_in, const int* in_sizes, int n_in,
                              void* d_out, int out_size, void* d_ws, size_t ws_size,
                              hipStream_t stream) {
    const float* local_feat  = (const float*)d_in[0];
    const float* global_feat = (const float*)d_in[1];
    const float* text_feat   = (const float*)d_in[2];
    const float* pos_l       = (const float*)d_in[3];
    const float* pos_g       = (const float*)d_in[4];
    const float* fc_w        = (const float*)d_in[5];
    const float* fc_b        = (const float*)d_in[6];
    const float* lg_in_w     = (const float*)d_in[7];
    const float* lg_in_b     = (const float*)d_in[8];
    const float* lg_out_w    = (const float*)d_in[9];
    const float* lg_out_b    = (const float*)d_in[10];
    const float* vt_in_w     = (const float*)d_in[11];
    const float* vt_in_b     = (const float*)d_in[12];
    const float* vt_out_w    = (const float*)d_in[13];
    const float* vt_out_b    = (const float*)d_in[14];
    const float* ml_in_w     = (const float*)d_in[15];
    const float* ml_in_b     = (const float*)d_in[16];
    const float* ml_out_w    = (const float*)d_in[17];
    const float* ml_out_b    = (const float*)d_in[18];
    float* out = (float*)d_out;

    const ull TE = (ull)NTOK * EMB;
    const ull EE = (ull)EMB * EMB;
    unsigned short* w = (unsigned short*)d_ws;
    Bufs B;
    for (int i = 0; i < 6; ++i) { B.Ph[i] = w + (2 * i) * TE; B.Pl[i] = w + (2 * i + 1) * TE; }
    B.ATTh  = w + 12 * TE;              // 2 TE (batch 2)
    B.QK    = w + 14 * TE;              // 4 TE (batch 2)
    B.VT    = w + 18 * TE;              // 2 TE
    B.Opart = w + 20 * TE;              // 4 TE
    B.ml    = (float*)(w + 24 * TE);    // 1 MB
    B.Wih   = w + 25 * TE;              // 3 EE
    B.Woh   = B.Wih + 3 * EE;           // EE
    B.Wol   = B.Woh + EE;               // EE

    add_pos_pair<<<TE / 1024, 256, 0, stream>>>(local_feat, pos_l, B.Ph[0], B.Pl[0]);
    add_pos_pair<<<TE / 1024, 256, 0, stream>>>(global_feat, pos_g, B.Ph[1], B.Pl[1]);

    // tf = text @ fc_w^T + fc_b -> P2 pair (text pair staged in QK scratch,
    // fc weight pair in Woh/Wol — both overwritten by the first mha round)
    split_pair<<<TE / 1024, 256, 0, stream>>>(text_feat, B.QK, B.QK + TE);
    split_pair<<<EE / 1024, 256, 0, stream>>>(fc_w, B.Woh, B.Wol);
    G<3, 2>(dim3(EMB / 128, NTOK / 128), B.QK, B.QK + TE, EMB, 0, B.Woh, B.Wol, EMB, 0,
            B.Ph[2], B.Pl[2], EMB, 0, EMB, 1.f, fc_b, 0, nullptr, nullptr, 0, 0, stream);

    const ll T2 = (ll)2 * TE, T4 = (ll)4 * TE;
    // round 1: local_global = mha(lf, gf; lg) + lf           -> P3
    run_mha(1, B.Ph[0], 0, B.Ph[1], 0, lg_in_w, lg_in_b, lg_out_w, lg_out_b,
            B.Ph[3], B.Pl[3], B.Ph[0], B.Pl[0], 0, 1, B, true, stream);
    // round 2 (batch): text_local = mha(tf, lf; vt)+lf -> P4
    //                  text_global = mha(tf, gf; vt)+tf -> P5
    run_mha(2, B.Ph[2], 0, B.Ph[0], T2, vt_in_w, vt_in_b, vt_out_w, vt_out_b,
            B.Ph[4], B.Pl[4], B.Ph[0], B.Pl[0], T4, 1, B, true, stream);
    // round 3 (batch): gt_gl = mha(P3, P5; ml) -> P0
    //                  gl_lt = mha(P4, P3; ml) -> P1
    run_mha(2, B.Ph[3], T2, B.Ph[5], -T4, ml_in_w, ml_in_b, ml_out_w, ml_out_b,
            B.Ph[0], B.Pl[0], nullptr, nullptr, 0, 0, B, true, stream);
    // round 4: full = mha(gl_lt=P1, gt_gl=P0; ml)            -> P3
    run_mha(1, B.Ph[1], 0, B.Ph[0], 0, ml_in_w, ml_in_b, ml_out_w, ml_out_b,
            B.Ph[3], B.Pl[3], nullptr, nullptr, 0, 0, B, false, stream);
    // round 5: fusion = mha(tf=P2, full=P3; ml) * tf         -> P4
    run_mha(1, B.Ph[2], 0, B.Ph[3], 0, ml_in_w, ml_in_b, ml_out_w, ml_out_b,
            B.Ph[4], B.Pl[4], B.Ph[2], B.Pl[2], 0, 2, B, false, stream);

    l2norm_rows<false><<<NTOK, 256, 0, stream>>>(nullptr, B.Ph[4], B.Pl[4], B.Ph[4], B.Pl[4]);
    l2norm_rows<true ><<<NTOK, 256, 0, stream>>>(local_feat, nullptr, nullptr, B.Ph[5], B.Pl[5]);

    G<3, 0>(dim3(QTY / 128, QTY / 128, 8),
            B.Ph[4], B.Pl[4], EMB, (ll)QTY * EMB,
            B.Ph[5], B.Pl[5], EMB, (ll)QTY * EMB,
            out, nullptr, QTY, (ll)QTY * QTY,
            EMB, 1.f, nullptr, 0, nullptr, nullptr, 0, 0, stream);
}

// Round 12
// 1686.998 us; speedup vs baseline: 1.2141x; 1.2141x over previous
//
#include <hip/hip_runtime.h>
#include <hip/hip_bf16.h>

// FilterModule: 7x MHA fusion pipeline, bf16 MFMA + flash attention v11.
// v11 = v9 (measured-best 1900us) + launch-shape wins:
//   - flash template<NSPLIT>: batch>=2 rounds use NSPLIT=1, write normalized O
//     directly to ATTh (no Opart round-trip, no combine)
//   - Q-proj+K-proj merged into one dispatch (gemm_qkproj, z = {q,k} x batch)
// Flash math/structure = v7 (8 waves x 16q, KVB=64 dbuf, VGPR 96, no spill).

typedef __attribute__((ext_vector_type(8))) short short8;
typedef __attribute__((ext_vector_type(4))) float f32x4;
typedef unsigned long long ull;
typedef long long ll;

namespace {
constexpr int NTOK = 4096;
constexpr int EMB  = 1024;
constexpr int QTY  = 512;
}

__device__ __forceinline__ float bf2f(unsigned short u) {
    union { float f; unsigned int i; } x; x.i = ((unsigned int)u) << 16; return x.f;
}
__device__ __forceinline__ unsigned short f2bf(float f) {
    union { float f; unsigned int i; } x; x.f = f;
    unsigned int r = x.i + 0x7fffu + ((x.i >> 16) & 1u);
    return (unsigned short)(r >> 16);
}

#define GLOAD_LDS16(g, l) __builtin_amdgcn_global_load_lds( \
    (const __attribute__((address_space(1))) void*)(g),     \
    (__attribute__((address_space(3))) void*)(l), 16, 0, 0)

// ---------------------------------------------------------------------------
// MFMA GEMM (B^T layout): C[m][n] = alpha*sum_k A[m][k]*B[n][k] (+epilogue).
// 128x128 tile, BK=32, 256 thr. Signed z-strides for batched launches.
// SPLITS: 1 = Ah*Bh; 2 = Ah*(Bh+Bl); 3 = (Ah+Al)*(Bh+Bl) minus ll term.
// OUTM: 0=f32, 1=bf16, 2=split pair. biasRow: bias indexed by row (else col).
template<int SPLITS, int OUTM>
__global__ __launch_bounds__(256)
void gemm_mfma(const unsigned short* __restrict__ Ah, const unsigned short* __restrict__ Al,
               int lda, ll sAz,
               const unsigned short* __restrict__ Bh, const unsigned short* __restrict__ Bl,
               int ldb, ll sBz,
               void* __restrict__ Cp, void* __restrict__ Clp,
               int ldc, ll sCz,
               int K, float alpha, const float* __restrict__ bias, int biasRow,
               const unsigned short* __restrict__ resH, const unsigned short* __restrict__ resL,
               ll sRz, int resMode)
{
    constexpr int NTILES = (SPLITS == 3 ? 4 : (SPLITS == 2 ? 3 : 2));
    constexpr int TSZ = 128 * 32;
    __shared__ unsigned short lds[NTILES * TSZ];  // Ah | Bh | [Bl] | [Al]
    const int tid  = threadIdx.x;
    const int brow = blockIdx.y * 128;
    const int bcol = blockIdx.x * 128;
    const ll   z   = blockIdx.z;
    Ah += z * sAz; Bh += z * sBz;
    if constexpr (SPLITS == 3) Al += z * sAz;
    if constexpr (SPLITS >= 2) Bl += z * sBz;

    const int lane = tid & 63;
    const int wv = tid >> 6, wr = wv >> 1, wc = wv & 1;
    const int l15 = lane & 15, l4 = lane >> 4;

    f32x4 acc[4][4];
    #pragma unroll
    for (int m = 0; m < 4; ++m)
        #pragma unroll
        for (int n = 0; n < 4; ++n) acc[m][n] = (f32x4){0.f, 0.f, 0.f, 0.f};

    for (int k0 = 0; k0 < K; k0 += 32) {
        #pragma unroll
        for (int i = 0; i < 2; ++i) {
            int idx = tid + i * 256;
            int row = idx >> 2;
            int kc  = (idx & 3) ^ ((row >> 1) & 3);
            GLOAD_LDS16(Ah + (ull)(brow + row) * lda + k0 + kc * 8, &lds[idx * 8]);
            GLOAD_LDS16(Bh + (ull)(bcol + row) * ldb + k0 + kc * 8, &lds[TSZ + idx * 8]);
            if constexpr (SPLITS >= 2)
                GLOAD_LDS16(Bl + (ull)(bcol + row) * ldb + k0 + kc * 8, &lds[2 * TSZ + idx * 8]);
            if constexpr (SPLITS == 3)
                GLOAD_LDS16(Al + (ull)(brow + row) * lda + k0 + kc * 8, &lds[3 * TSZ + idx * 8]);
        }
        __syncthreads();

        short8 ah[4], bh[4], bl2[4], al2[4];
        #pragma unroll
        for (int m = 0; m < 4; ++m) {
            int rr = wr * 64 + m * 16 + l15;
            int sl = l4 ^ ((rr >> 1) & 3);
            int off = rr * 32 + sl * 8;
            ah[m] = *(const short8*)&lds[off];
            if constexpr (SPLITS == 3) al2[m] = *(const short8*)&lds[3 * TSZ + off];
        }
        #pragma unroll
        for (int n = 0; n < 4; ++n) {
            int rr = wc * 64 + n * 16 + l15;
            int sl = l4 ^ ((rr >> 1) & 3);
            int off = rr * 32 + sl * 8;
            bh[n] = *(const short8*)&lds[TSZ + off];
            if constexpr (SPLITS >= 2) bl2[n] = *(const short8*)&lds[2 * TSZ + off];
        }
        #pragma unroll
        for (int m = 0; m < 4; ++m)
            #pragma unroll
            for (int n = 0; n < 4; ++n) {
                acc[m][n] = __builtin_amdgcn_mfma_f32_16x16x32_bf16(ah[m], bh[n], acc[m][n], 0, 0, 0);
                if constexpr (SPLITS >= 2)
                    acc[m][n] = __builtin_amdgcn_mfma_f32_16x16x32_bf16(ah[m], bl2[n], acc[m][n], 0, 0, 0);
                if constexpr (SPLITS == 3)
                    acc[m][n] = __builtin_amdgcn_mfma_f32_16x16x32_bf16(al2[m], bh[n], acc[m][n], 0, 0, 0);
            }
        __syncthreads();
    }

    float* Cf = (float*)Cp + z * sCz;
    unsigned short* Ch = (unsigned short*)Cp + z * sCz;
    unsigned short* Cl = (unsigned short*)Clp + z * sCz;
    const unsigned short* rH = resH + z * sRz;
    const unsigned short* rL = resL + z * sRz;
    const int rowB = brow + wr * 64 + l4 * 4;
    const int colB = bcol + wc * 64 + l15;
    #pragma unroll
    for (int n = 0; n < 4; ++n) {
        int col = colB + n * 16;
        #pragma unroll
        for (int m = 0; m < 4; ++m) {
            #pragma unroll
            for (int r = 0; r < 4; ++r) {
                int row = rowB + m * 16 + r;
                ull ci = (ull)row * ldc + col;
                float v = acc[m][n][r] * alpha;
                if (bias) v += biasRow ? bias[row] : bias[col];
                if (resMode == 1)      v += bf2f(rH[ci]) + bf2f(rL[ci]);
                else if (resMode == 2) v *= bf2f(rH[ci]) + bf2f(rL[ci]);
                if constexpr (OUTM == 0)      Cf[ci] = v;
                else if constexpr (OUTM == 1) Ch[ci] = f2bf(v);
                else {
                    unsigned short h = f2bf(v);
                    Ch[ci] = h;
                    Cl[ci] = f2bf(v - bf2f(h));
                }
            }
        }
    }
}

// ---------------------------------------------------------------------------
// Fused Q+K projection. z = b*2 + j (j: 0=Q, 1=K). A base per z from args;
// B = W + j*EE; C = QK[b][:, j*1024 .. j*1024+1024]; bias = in_b + j*1024.
// SPLITS=1, OUTM=bf16, 128x128 tile, BK=32.
__global__ __launch_bounds__(256)
void gemm_qkproj(const unsigned short* a0, const unsigned short* a1,
                 const unsigned short* a2, const unsigned short* a3,
                 const unsigned short* __restrict__ W,
                 unsigned short* __restrict__ QK,
                 const float* __restrict__ bias)
{
    constexpr int TSZ = 128 * 32;
    __shared__ unsigned short lds[2 * TSZ];
    const int tid  = threadIdx.x;
    const int brow = blockIdx.y * 128;
    const int bcol = blockIdx.x * 128;
    const int z = blockIdx.z;
    const int j = z & 1, bb = z >> 1;
    const unsigned short* Ah = (z == 0) ? a0 : (z == 1) ? a1 : (z == 2) ? a2 : a3;
    const unsigned short* Bh = W + (ull)j * EMB * EMB;
    unsigned short* C = QK + (ull)bb * NTOK * 2048 + j * 1024;
    const float* bi = bias + j * 1024;

    const int lane = tid & 63;
    const int wv = tid >> 6, wr = wv >> 1, wc = wv & 1;
    const int l15 = lane & 15, l4 = lane >> 4;

    f32x4 acc[4][4];
    #pragma unroll
    for (int m = 0; m < 4; ++m)
        #pragma unroll
        for (int n = 0; n < 4; ++n) acc[m][n] = (f32x4){0.f, 0.f, 0.f, 0.f};

    for (int k0 = 0; k0 < EMB; k0 += 32) {
        #pragma unroll
        for (int i = 0; i < 2; ++i) {
            int idx = tid + i * 256;
            int row = idx >> 2;
            int kc  = (idx & 3) ^ ((row >> 1) & 3);
            GLOAD_LDS16(Ah + (ull)(brow + row) * EMB + k0 + kc * 8, &lds[idx * 8]);
            GLOAD_LDS16(Bh + (ull)(bcol + row) * EMB + k0 + kc * 8, &lds[TSZ + idx * 8]);
        }
        __syncthreads();

        short8 ah[4], bh[4];
        #pragma unroll
        for (int m = 0; m < 4; ++m) {
            int rr = wr * 64 + m * 16 + l15;
            int sl = l4 ^ ((rr >> 1) & 3);
            ah[m] = *(const short8*)&lds[rr * 32 + sl * 8];
        }
        #pragma unroll
        for (int n = 0; n < 4; ++n) {
            int rr = wc * 64 + n * 16 + l15;
            int sl = l4 ^ ((rr >> 1) & 3);
            bh[n] = *(const short8*)&lds[TSZ + rr * 32 + sl * 8];
        }
        #pragma unroll
        for (int m = 0; m < 4; ++m)
            #pragma unroll
            for (int n = 0; n < 4; ++n)
                acc[m][n] = __builtin_amdgcn_mfma_f32_16x16x32_bf16(ah[m], bh[n], acc[m][n], 0, 0, 0);
        __syncthreads();
    }

    const int rowB = brow + wr * 64 + l4 * 4;
    const int colB = bcol + wc * 64 + l15;
    #pragma unroll
    for (int n = 0; n < 4; ++n) {
        int col = colB + n * 16;
        float bv = bi[col];
        #pragma unroll
        for (int m = 0; m < 4; ++m)
            #pragma unroll
            for (int r = 0; r < 4; ++r) {
                int row = rowB + m * 16 + r;
                C[(ull)row * 2048 + col] = f2bf(acc[m][n][r] + bv);
            }
    }
}

// ---------------------------------------------------------------------------
// Flash attention (v7 structure + batch + NSPLIT). QK [batch][4096][2048];
// VT [batch][1024][4096]. blockIdx.z = batch*4 + head.
// NSPLIT=2: unnormalized-per-split path -> Opart (normalized bf16) + ml.
// NSPLIT=1: full KV sweep, write normalized O directly to attH (no combine).
template<int NSPLIT>
__global__ __launch_bounds__(512)
void flash_attn(const unsigned short* __restrict__ QK,
                const unsigned short* __restrict__ VT,
                unsigned short* __restrict__ Opart, float* __restrict__ ml,
                unsigned short* __restrict__ attH)
{
    constexpr int KVB = 64;
    constexpr int NTILE = (NTOK / NSPLIT) / KVB;
    __shared__ unsigned short Kt[2][KVB * 256];   // [kv][d], 16B-chunk-swizzled
    __shared__ unsigned short Vt[2][256 * KVB];   // [d][kv], swizzled

    const int tid = threadIdx.x;
    const int w = tid >> 6, lane = tid & 63;
    const int l15 = lane & 15, l4 = lane >> 4;
    const int qt = blockIdx.x, sp = blockIdx.y;
    const int zb = blockIdx.z, b = zb >> 2, h = zb & 3;
    const int qrow = qt * 128 + w * 16 + l15;
    const int kv0 = sp * (NTOK / NSPLIT);
    const unsigned short* QKb = QK + (ull)b * NTOK * 2048;
    const unsigned short* VTb = VT + (ull)b * 1024 * 4096;

    // Q fragments in registers, pre-scaled by 1/sqrt(d)=1/16 (exact in bf16)
    short8 qreg[8];
    {
        const unsigned short* qp = QKb + (ull)qrow * 2048 + h * 256;
        #pragma unroll
        for (int c = 0; c < 8; ++c) {
            short8 x = *(const short8*)&qp[c * 32 + l4 * 8];
            #pragma unroll
            for (int j = 0; j < 8; ++j)
                x[j] = (short)f2bf(bf2f((unsigned short)x[j]) * 0.0625f);
            qreg[c] = x;
        }
    }

    f32x4 oacc[16];
    #pragma unroll
    for (int dn = 0; dn < 16; ++dn) oacc[dn] = (f32x4){0.f, 0.f, 0.f, 0.f};
    float m_r = -1e30f, l_r = 0.f;

    auto stage = [&](int t, int buf) {
        int base = kv0 + t * KVB;
        #pragma unroll
        for (int i = 0; i < 4; ++i) {       // K tile: 64 rows x 32 chunks
            int s = tid + i * 512;
            int r = s >> 5, c = s & 31;
            int c0 = c ^ (r & 7);
            GLOAD_LDS16(QKb + (ull)(base + r) * 2048 + 1024 + h * 256 + c0 * 8,
                        &Kt[buf][s * 8]);
        }
        #pragma unroll
        for (int i = 0; i < 4; ++i) {       // V^T tile: 256 rows x 8 chunks
            int s = tid + i * 512;
            int r = s >> 3, c = s & 7;
            int c0 = c ^ (r & 7);
            GLOAD_LDS16(VTb + (ull)(h * 256 + r) * 4096 + base + c0 * 8,
                        &Vt[buf][s * 8]);
        }
    };

    stage(0, 0);
    for (int t = 0; t < NTILE; ++t) {
        if (t + 1 < NTILE) {
            stage(t + 1, (t + 1) & 1);
            asm volatile("s_waitcnt vmcnt(8)");
        } else {
            asm volatile("s_waitcnt vmcnt(0)");
        }
        __builtin_amdgcn_s_barrier();

        const unsigned short* Kb = Kt[t & 1];
        const unsigned short* Vb = Vt[t & 1];

        // QK^T (swapped): sacc[fk] = S^T tile, lane: q=l15, kv=fk*16+l4*4+r
        f32x4 sacc[4];
        #pragma unroll
        for (int fk = 0; fk < 4; ++fk) sacc[fk] = (f32x4){0.f, 0.f, 0.f, 0.f};
        #pragma unroll
        for (int fk = 0; fk < 4; ++fk) {
            int r = fk * 16 + l15;
            int rx = r & 7;
            #pragma unroll
            for (int c = 0; c < 8; ++c) {
                int ch = (4 * c + l4) ^ rx;
                short8 kf = *(const short8*)&Kb[r * 256 + ch * 8];
                sacc[fk] = __builtin_amdgcn_mfma_f32_16x16x32_bf16(kf, qreg[c], sacc[fk], 0, 0, 0);
            }
        }

        // online softmax (per q-row = per l15; reduce over l4 groups)
        float tm = sacc[0][0];
        #pragma unroll
        for (int fk = 0; fk < 4; ++fk)
            #pragma unroll
            for (int rr = 0; rr < 4; ++rr) tm = fmaxf(tm, sacc[fk][rr]);
        tm = fmaxf(tm, __shfl_xor(tm, 16));
        tm = fmaxf(tm, __shfl_xor(tm, 32));

        bool nomax = __all(tm <= m_r);
        float mnew = nomax ? m_r : fmaxf(m_r, tm);
        if (!nomax) {
            float corr = __expf(m_r - mnew);
            float c4[4];
            #pragma unroll
            for (int r = 0; r < 4; ++r) c4[r] = __shfl(corr, l4 * 4 + r);
            #pragma unroll
            for (int dn = 0; dn < 16; ++dn)
                #pragma unroll
                for (int r = 0; r < 4; ++r) oacc[dn][r] *= c4[r];
            l_r *= corr;
            m_r = mnew;
        }

        float p[16]; float ls = 0.f;
        #pragma unroll
        for (int fk = 0; fk < 4; ++fk)
            #pragma unroll
            for (int rr = 0; rr < 4; ++rr) {
                float e = __expf(sacc[fk][rr] - m_r);
                p[fk * 4 + rr] = e; ls += e;
            }
        ls += __shfl_xor(ls, 16);
        ls += __shfl_xor(ls, 32);
        l_r += ls;

        // pack P to bf16 pairs: W[f][pp] = kv (16f+4*l4+2pp, +1) for q=l15
        unsigned int W[4][2];
        #pragma unroll
        for (int f = 0; f < 4; ++f)
            #pragma unroll
            for (int pp = 0; pp < 2; ++pp)
                W[f][pp] = (unsigned int)f2bf(p[f * 4 + 2 * pp]) |
                           ((unsigned int)f2bf(p[f * 4 + 2 * pp + 1]) << 16);

        // gather to A-frag layout: lane q=l15, kv = c*32 + l4*8 + j
        const int sbase = l15 + ((l4 & 1) << 5);
        const bool hi = (l4 >> 1) & 1;
        #pragma unroll
        for (int kvc = 0; kvc < 2; ++kvc) {
            unsigned int a0 = (unsigned int)__shfl((int)W[2 * kvc][0], sbase);
            unsigned int a1 = (unsigned int)__shfl((int)W[2 * kvc][1], sbase);
            unsigned int a2 = (unsigned int)__shfl((int)W[2 * kvc][0], sbase + 16);
            unsigned int a3 = (unsigned int)__shfl((int)W[2 * kvc][1], sbase + 16);
            unsigned int b0 = (unsigned int)__shfl((int)W[2 * kvc + 1][0], sbase);
            unsigned int b1 = (unsigned int)__shfl((int)W[2 * kvc + 1][1], sbase);
            unsigned int b2 = (unsigned int)__shfl((int)W[2 * kvc + 1][0], sbase + 16);
            unsigned int b3 = (unsigned int)__shfl((int)W[2 * kvc + 1][1], sbase + 16);
            union { unsigned int u[4]; short8 s8; } pa;
            pa.u[0] = hi ? b0 : a0; pa.u[1] = hi ? b1 : a1;
            pa.u[2] = hi ? b2 : a2; pa.u[3] = hi ? b3 : a3;

            // PV: oacc[dn] += P[q, kv32] * V^T[d, kv32]
            #pragma unroll
            for (int dn = 0; dn < 16; ++dn) {
                int row = dn * 16 + l15;
                int ch = (kvc * 4 + l4) ^ (row & 7);
                short8 vf = *(const short8*)&Vb[row * 64 + ch * 8];
                oacc[dn] = __builtin_amdgcn_mfma_f32_16x16x32_bf16(pa.s8, vf, oacc[dn], 0, 0, 0);
            }
        }
        __builtin_amdgcn_s_barrier();
    }

    // epilogue: normalized O (bf16). lane: d=dn*16+l15, q=base+l4*4+r
    float inv = 1.f / l_r;
    float i4[4];
    #pragma unroll
    for (int r = 0; r < 4; ++r) i4[r] = __shfl(inv, l4 * 4 + r);

    if constexpr (NSPLIT == 2) {
        unsigned short* Ob = Opart + (((ull)b * 2 + sp) * 4 + h) * NTOK * 256;
        #pragma unroll
        for (int dn = 0; dn < 16; ++dn) {
            int d = dn * 16 + l15;
            #pragma unroll
            for (int r = 0; r < 4; ++r) {
                int q = qt * 128 + w * 16 + l4 * 4 + r;
                Ob[(ull)q * 256 + d] = f2bf(oacc[dn][r] * i4[r]);
            }
        }
        if (l4 == 0) {
            float2* mlp = (float2*)ml + (((ull)b * 2 + sp) * 4 + h) * NTOK + qrow;
            *mlp = make_float2(m_r, l_r);
        }
    } else {
        unsigned short* Ob = attH + (ull)b * NTOK * EMB;
        #pragma unroll
        for (int dn = 0; dn < 16; ++dn) {
            int d = dn * 16 + l15;
            #pragma unroll
            for (int r = 0; r < 4; ++r) {
                int q = qt * 128 + w * 16 + l4 * 4 + r;
                Ob[(ull)q * EMB + h * 256 + d] = f2bf(oacc[dn][r] * i4[r]);
            }
        }
    }
}

// ---------------------------------------------------------------------------
// merge 2 KV-split partials (normalized bf16) -> att bf16 (hi only).
// blockIdx.x = batch*4096 + q.
__global__ __launch_bounds__(256)
void flash_combine(const unsigned short* __restrict__ Opart, const float* __restrict__ ml,
                   unsigned short* __restrict__ attH)
{
    const int bx = blockIdx.x;
    const int b = bx >> 12, q = bx & 4095;
    const int t = threadIdx.x;
    const int h = t >> 6, d4 = (t & 63) * 4;

    float2 m0 = ((const float2*)ml)[(((ull)b * 2 + 0) * 4 + h) * NTOK + q];
    float2 m1 = ((const float2*)ml)[(((ull)b * 2 + 1) * 4 + h) * NTOK + q];
    float ms = fmaxf(m0.x, m1.x);
    float w0 = __expf(m0.x - ms) * m0.y;
    float w1 = __expf(m1.x - ms) * m1.y;
    float inv = 1.f / (w0 + w1);
    w0 *= inv; w1 *= inv;

    ushort4 o0 = *(const ushort4*)&Opart[((((ull)b * 2 + 0) * 4 + h) * NTOK + q) * 256 + d4];
    ushort4 o1 = *(const ushort4*)&Opart[((((ull)b * 2 + 1) * 4 + h) * NTOK + q) * 256 + d4];
    ushort4 ho;
    ho.x = f2bf(w0 * bf2f(o0.x) + w1 * bf2f(o1.x));
    ho.y = f2bf(w0 * bf2f(o0.y) + w1 * bf2f(o1.y));
    ho.z = f2bf(w0 * bf2f(o0.z) + w1 * bf2f(o1.z));
    ho.w = f2bf(w0 * bf2f(o0.w) + w1 * bf2f(o1.w));
    *(ushort4*)&attH[(ull)b * NTOK * EMB + (ull)q * EMB + h * 256 + d4] = ho;
}

// ---------------------------------------------------------------------------
template<bool F32IN>
__global__ __launch_bounds__(256)
void l2norm_rows(const float* __restrict__ inF, const unsigned short* __restrict__ inH,
                 const unsigned short* __restrict__ inL,
                 unsigned short* __restrict__ oH, unsigned short* __restrict__ oL)
{
    const ull row = blockIdx.x;
    const int t = threadIdx.x;
    const int lane = t & 63, wid = t >> 6;
    __shared__ float red[4];

    float v[4];
    if constexpr (F32IN) {
        float4 x = *(const float4*)&inF[row * EMB + t * 4];
        v[0] = x.x; v[1] = x.y; v[2] = x.z; v[3] = x.w;
    } else {
        ushort4 hh = *(const ushort4*)&inH[row * EMB + t * 4];
        ushort4 ll2 = *(const ushort4*)&inL[row * EMB + t * 4];
        v[0] = bf2f(hh.x) + bf2f(ll2.x); v[1] = bf2f(hh.y) + bf2f(ll2.y);
        v[2] = bf2f(hh.z) + bf2f(ll2.z); v[3] = bf2f(hh.w) + bf2f(ll2.w);
    }
    float ss = v[0] * v[0] + v[1] * v[1] + v[2] * v[2] + v[3] * v[3];
    #pragma unroll
    for (int o = 32; o > 0; o >>= 1) ss += __shfl_down(ss, o);
    if (lane == 0) red[wid] = ss;
    __syncthreads();
    ss = red[0] + red[1] + red[2] + red[3];

    float inv = 1.f / fmaxf(sqrtf(ss), 1e-8f);
    ushort4 ho, lo;
    float s0 = v[0] * inv, s1 = v[1] * inv, s2 = v[2] * inv, s3 = v[3] * inv;
    ho.x = f2bf(s0); lo.x = f2bf(s0 - bf2f(ho.x));
    ho.y = f2bf(s1); lo.y = f2bf(s1 - bf2f(ho.y));
    ho.z = f2bf(s2); lo.z = f2bf(s2 - bf2f(ho.z));
    ho.w = f2bf(s3); lo.w = f2bf(s3 - bf2f(ho.w));
    *(ushort4*)&oH[row * EMB + t * 4] = ho;
    *(ushort4*)&oL[row * EMB + t * 4] = lo;
}

__global__ __launch_bounds__(256)
void add_pos_pair(const float* __restrict__ in, const float* __restrict__ pos,
                  unsigned short* __restrict__ oH, unsigned short* __restrict__ oL)
{
    ull i = ((ull)blockIdx.x * 256 + threadIdx.x) * 4;
    float4 a = *(const float4*)&in[i];
    float4 p = *(const float4*)&pos[(int)(i & (EMB - 1))];
    float w[4] = { a.x + p.x, a.y + p.y, a.z + p.z, a.w + p.w };
    ushort4 ho, lo;
    ho.x = f2bf(w[0]); lo.x = f2bf(w[0] - bf2f(ho.x));
    ho.y = f2bf(w[1]); lo.y = f2bf(w[1] - bf2f(ho.y));
    ho.z = f2bf(w[2]); lo.z = f2bf(w[2] - bf2f(ho.z));
    ho.w = f2bf(w[3]); lo.w = f2bf(w[3] - bf2f(ho.w));
    *(ushort4*)&oH[i] = ho;
    *(ushort4*)&oL[i] = lo;
}

__global__ __launch_bounds__(256)
void split_pair(const float* __restrict__ in, unsigned short* __restrict__ oH,
                unsigned short* __restrict__ oL)
{
    ull i = ((ull)blockIdx.x * 256 + threadIdx.x) * 4;
    float4 a = *(const float4*)&in[i];
    float w[4] = { a.x, a.y, a.z, a.w };
    ushort4 ho, lo;
    ho.x = f2bf(w[0]); lo.x = f2bf(w[0] - bf2f(ho.x));
    ho.y = f2bf(w[1]); lo.y = f2bf(w[1] - bf2f(ho.y));
    ho.z = f2bf(w[2]); lo.z = f2bf(w[2] - bf2f(ho.z));
    ho.w = f2bf(w[3]); lo.w = f2bf(w[3] - bf2f(ho.w));
    *(ushort4*)&oH[i] = ho;
    *(ushort4*)&oL[i] = lo;
}

// f32 -> bf16 cast (hi only), 4 elems/thread
__global__ __launch_bounds__(256)
void cast_bf16(const float* __restrict__ in, unsigned short* __restrict__ out)
{
    ull i = ((ull)blockIdx.x * 256 + threadIdx.x) * 4;
    float4 a = *(const float4*)&in[i];
    ushort4 ho;
    ho.x = f2bf(a.x); ho.y = f2bf(a.y); ho.z = f2bf(a.z); ho.w = f2bf(a.w);
    *(ushort4*)&out[i] = ho;
}

// ---------------------------------------------------------------------------
namespace {

template<int S, int O>
inline void G(dim3 grid,
              const unsigned short* Ah, const unsigned short* Al, int lda, ll sAz,
              const unsigned short* Bh, const unsigned short* Bl, int ldb, ll sBz,
              void* Ch, void* Cl, int ldc, ll sCz,
              int K, float alpha, const float* bias, int biasRow,
              const unsigned short* rh, const unsigned short* rl, ll sRz, int rm,
              hipStream_t st)
{
    gemm_mfma<S, O><<<grid, dim3(256), 0, st>>>(Ah, Al, lda, sAz, Bh, Bl, ldb, sBz,
                                                Ch, Cl, ldc, sCz, K, alpha, bias, biasRow,
                                                rh, rl, sRz, rm);
}

struct Bufs {
    unsigned short *Ph[6], *Pl[6];
    unsigned short *ATTh, *QK, *VT, *Wih, *Woh, *Wol, *Opart;
    float *ml;
};

// batch mhas sharing (in_w,out_w): z in [0,batch). q input = qh + z*sQ,
// k/v input = kh + z*sK, dest = dsth/dstl + z*2TE, res = resh/resl + z*sR.
void run_mha(int batch,
             const unsigned short* qh, ll sQ,
             const unsigned short* kh, ll sK,
             const float* in_w, const float* in_b,
             const float* out_w, const float* out_b,
             unsigned short* dsth, unsigned short* dstl,
             const unsigned short* resh, const unsigned short* resl, ll sR, int resMode,
             const Bufs& B, bool convW, hipStream_t s)
{
    const ull EE = (ull)EMB * EMB;
    const ll  TE = (ll)NTOK * EMB;
    const ll  VTBS = (ll)1024 * 4096;
    if (convW) {
        cast_bf16<<<3 * EE / 1024, 256, 0, s>>>(in_w, B.Wih);
        split_pair<<<EE / 1024, 256, 0, s>>>(out_w, B.Woh, B.Wol);
    }
    // fused Q+K projection: z = b*2 + {0:Q, 1:K}
    gemm_qkproj<<<dim3(8, 32, 2 * batch), 256, 0, s>>>(
        qh, kh, qh + sQ, kh + sK, B.Wih, B.QK, in_b);
    // V^T proj: C[b][d][token] = Wv[d,:]·feat[token,:] + b_v[d]  (bias-row)
    G<1, 1>(dim3(32, 8, batch), B.Wih + 2 * EE, nullptr, EMB, 0, kh, nullptr, EMB, sK,
            B.VT, nullptr, 4096, VTBS, EMB, 1.f, in_b + 2 * EMB, 1, nullptr, nullptr, 0, 0, s);

    if (batch == 1) {
        flash_attn<2><<<dim3(32, 2, 4), 512, 0, s>>>(B.QK, B.VT, B.Opart, B.ml, B.ATTh);
        flash_combine<<<NTOK, 256, 0, s>>>(B.Opart, B.ml, B.ATTh);
    } else {
        flash_attn<1><<<dim3(32, 1, 4 * batch), 512, 0, s>>>(B.QK, B.VT, B.Opart, B.ml, B.ATTh);
    }

    // out-proj: A = att (hi only) x weight pair -> dest pair (+res epilogue)
    G<2, 2>(dim3(8, 32, batch), B.ATTh, nullptr, EMB, TE, B.Woh, B.Wol, EMB, 0,
            dsth, dstl, EMB, 2 * TE, EMB, 1.f, out_b, 0, resh, resl, sR, resMode, s);
}

} // namespace

extern "C" void kernel_launch(void* const* d_in, const int* in_sizes, int n_in,
                              void* d_out, int out_size, void* d_ws, size_t ws_size,
                              hipStream_t stream) {
    const float* local_feat  = (const float*)d_in[0];
    const float* global_feat = (const float*)d_in[1];
    const float* text_feat   = (const float*)d_in[2];
    const float* pos_l       = (const float*)d_in[3];
    const float* pos_g       = (const float*)d_in[4];
    const float* fc_w        = (const float*)d_in[5];
    const float* fc_b        = (const float*)d_in[6];
    const float* lg_in_w     = (const float*)d_in[7];
    const float* lg_in_b     = (const float*)d_in[8];
    const float* lg_out_w    = (const float*)d_in[9];
    const float* lg_out_b    = (const float*)d_in[10];
    const float* vt_in_w     = (const float*)d_in[11];
    const float* vt_in_b     = (const float*)d_in[12];
    const float* vt_out_w    = (const float*)d_in[13];
    const float* vt_out_b    = (const float*)d_in[14];
    const float* ml_in_w     = (const float*)d_in[15];
    const float* ml_in_b     = (const float*)d_in[16];
    const float* ml_out_w    = (const float*)d_in[17];
    const float* ml_out_b    = (const float*)d_in[18];
    float* out = (float*)d_out;

    const ull TE = (ull)NTOK * EMB;
    const ull EE = (ull)EMB * EMB;
    unsigned short* w = (unsigned short*)d_ws;
    Bufs B;
    for (int i = 0; i < 6; ++i) { B.Ph[i] = w + (2 * i) * TE; B.Pl[i] = w + (2 * i + 1) * TE; }
    B.ATTh  = w + 12 * TE;              // 2 TE (batch 2)
    B.QK    = w + 14 * TE;              // 4 TE (batch 2)
    B.VT    = w + 18 * TE;              // 2 TE
    B.Opart = w + 20 * TE;              // 2 TE (batch-1 rounds only)
    B.ml    = (float*)(w + 24 * TE);    // 1 MB
    B.Wih   = w + 25 * TE;              // 3 EE
    B.Woh   = B.Wih + 3 * EE;           // EE
    B.Wol   = B.Woh + EE;               // EE

    add_pos_pair<<<TE / 1024, 256, 0, stream>>>(local_feat, pos_l, B.Ph[0], B.Pl[0]);
    add_pos_pair<<<TE / 1024, 256, 0, stream>>>(global_feat, pos_g, B.Ph[1], B.Pl[1]);

    // tf = text @ fc_w^T + fc_b -> P2 pair (text pair staged in QK scratch,
    // fc weight pair in Woh/Wol — both overwritten by the first mha round)
    split_pair<<<TE / 1024, 256, 0, stream>>>(text_feat, B.QK, B.QK + TE);
    split_pair<<<EE / 1024, 256, 0, stream>>>(fc_w, B.Woh, B.Wol);
    G<3, 2>(dim3(EMB / 128, NTOK / 128), B.QK, B.QK + TE, EMB, 0, B.Woh, B.Wol, EMB, 0,
            B.Ph[2], B.Pl[2], EMB, 0, EMB, 1.f, fc_b, 0, nullptr, nullptr, 0, 0, stream);

    const ll T2 = (ll)2 * TE, T4 = (ll)4 * TE;
    // round 1: local_global = mha(lf, gf; lg) + lf           -> P3
    run_mha(1, B.Ph[0], 0, B.Ph[1], 0, lg_in_w, lg_in_b, lg_out_w, lg_out_b,
            B.Ph[3], B.Pl[3], B.Ph[0], B.Pl[0], 0, 1, B, true, stream);
    // round 2 (batch): text_local = mha(tf, lf; vt)+lf -> P4
    //                  text_global = mha(tf, gf; vt)+tf -> P5
    run_mha(2, B.Ph[2], 0, B.Ph[0], T2, vt_in_w, vt_in_b, vt_out_w, vt_out_b,
            B.Ph[4], B.Pl[4], B.Ph[0], B.Pl[0], T4, 1, B, true, stream);
    // round 3 (batch): gt_gl = mha(P3, P5; ml) -> P0
    //                  gl_lt = mha(P4, P3; ml) -> P1
    run_mha(2, B.Ph[3], T2, B.Ph[5], -T4, ml_in_w, ml_in_b, ml_out_w, ml_out_b,
            B.Ph[0], B.Pl[0], nullptr, nullptr, 0, 0, B, true, stream);
    // round 4: full = mha(gl_lt=P1, gt_gl=P0; ml)            -> P3
    run_mha(1, B.Ph[1], 0, B.Ph[0], 0, ml_in_w, ml_in_b, ml_out_w, ml_out_b,
            B.Ph[3], B.Pl[3], nullptr, nullptr, 0, 0, B, false, stream);
    // round 5: fusion = mha(tf=P2, full=P3; ml) * tf         -> P4
    run_mha(1, B.Ph[2], 0, B.Ph[3], 0, ml_in_w, ml_in_b, ml_out_w, ml_out_b,
            B.Ph[4], B.Pl[4], B.Ph[2], B.Pl[2], 0, 2, B, false, stream);

    l2norm_rows<false><<<NTOK, 256, 0, stream>>>(nullptr, B.Ph[4], B.Pl[4], B.Ph[4], B.Pl[4]);
    l2norm_rows<true ><<<NTOK, 256, 0, stream>>>(local_feat, nullptr, nullptr, B.Ph[5], B.Pl[5]);

    G<3, 0>(dim3(QTY / 128, QTY / 128, 8),
            B.Ph[4], B.Pl[4], EMB, (ll)QTY * EMB,
            B.Ph[5], B.Pl[5], EMB, (ll)QTY * EMB,
            out, nullptr, QTY, (ll)QTY * QTY,
            EMB, 1.f, nullptr, 0, nullptr, nullptr, 0, 0, stream);
}